// Round 7
// baseline (355.293 us; speedup 1.0000x reference)
//
#include <hip/hip_runtime.h>

// ---------------------------------------------------------------------------
// MetaNet linearized model, MI355X.
//   f0 = xbar @ Wp + bp ; z = f0@W1 + b1 ; f = relu(z) ; base = f@W2 + b2
//   df0 = (c0 (x) xbar)@dWp + sum_t c1 dbp
//   dz  = df0@W1 + (c2 (x) f0)@dW1 + sum_t c3 db1 ; df = mask(z) dz
//   dout= df@W2 + (c4 (x) f)@dW2 + sum_t c5 db2 ; out = base + dout
// GEMM v7: 2-D fragment mapping. v4/v6 were LDS-pipe-bound because every
// lane re-read the whole 128B A-column (8 ds_read_b128 per wave-k). Now a
// lane owns 8 rows x 4 cols: per k = 2 ds_read_b128 (4 row-groups hit
// disjoint 32B chunks, conflict-free single instr) + 1 global float4 of B
// + 32 fmac -> LDS:VALU ~0.35. Waves split COLS (no cross-wave reduce);
// k splits across blocks only. B 4-deep float4 double-buffered (v4's
// proven never-drain discipline). ~140 VGPR, launch_bounds(256,3).
// ---------------------------------------------------------------------------

__global__ void patch_partial_k(const float* __restrict__ x, float* __restrict__ part) {
    int blk = blockIdx.x;            // b*42 + ch*14 + i   (1344 blocks)
    int i  = blk % 14;
    int ch = (blk / 14) % 3;
    int b  = blk / 42;
    int t  = threadIdx.x;            // py*16 + px
    int py = t >> 4, px = t & 15;
    const float* xp = x + (((size_t)(b*3 + ch))*224 + (size_t)(i*16 + py))*224 + px;
    float s = 0.f;
#pragma unroll
    for (int j = 0; j < 14; ++j) s += xp[j*16];
    part[(size_t)blk*256 + t] = s;
}

__global__ void patch_reduce_k(const float* __restrict__ part, float* __restrict__ xbarT) {
    int idx = blockIdx.x*256 + threadIdx.x;   // 24576 = 32*768
    int b = idx / 768;
    int c = idx % 768;
    int ch = c >> 8, t = c & 255;
    const float* p = part + ((size_t)(b*42 + ch*14))*256 + t;
    float s = 0.f;
#pragma unroll
    for (int i = 0; i < 14; ++i) s += p[i*256];
    xbarT[(size_t)c*32 + b] = s * (1.f/196.f);
}

// P[y][col*32+row] = sum_{k in slice y} AT[k][row] * B[k][col]
// Block: 256 cols x 32 rows, KB k's. 4 waves = 4 col-groups of 64.
// Lane: rg=lane>>4 (rows rg*8..+8), cg=lane&15 (cols cg*4..+4), acc[r*4+c].
#define PREFA(AR, K)                                                  \
    { AR[0] = *(const float4*)(ap7 + (K)*32);                         \
      AR[1] = *(const float4*)(ap7 + (K)*32 + 4); }

#define LOADB4(BUF)                                                   \
    { _Pragma("unroll")                                               \
      for (int u = 0; u < 4; ++u)                                     \
          BUF[u] = *(const float4*)(bp7 + (size_t)u*N);               \
      bp7 += (size_t)4*N; }

#define FMA4(AV, B4, base)                                            \
    acc[(base)+0] += (AV)*(B4).x; acc[(base)+1] += (AV)*(B4).y;       \
    acc[(base)+2] += (AV)*(B4).z; acc[(base)+3] += (AV)*(B4).w;

#define FMACK(AR, B4)                                                 \
    { FMA4(AR[0].x, B4, 0)  FMA4(AR[0].y, B4, 4)                      \
      FMA4(AR[0].z, B4, 8)  FMA4(AR[0].w, B4, 12)                     \
      FMA4(AR[1].x, B4, 16) FMA4(AR[1].y, B4, 20)                     \
      FMA4(AR[1].z, B4, 24) FMA4(AR[1].w, B4, 28) }

template<int N, int KB>
__global__ __launch_bounds__(256, 3) void gemm7_k(const float* __restrict__ AT,
                                                  const float* __restrict__ Bm,
                                                  float* __restrict__ P) {
    __shared__ float As[KB*32 + 32];             // +32: tail PREFA pad
    const int tid  = threadIdx.x;
    const int lane = tid & 63;
    const int wave = tid >> 6;
    const int rg   = lane >> 4;                  // row group: rows rg*8..+8
    const int cg   = lane & 15;                  // col group: 4 cols
    const size_t kblk = (size_t)blockIdx.y * KB;

    // stage A tile (coalesced float4; generic count for any KB)
    {
        const float4* Ag = (const float4*)(AT + kblk*32);
        float4* As4 = (float4*)As;
        for (int i = tid; i < KB*8; i += 256) As4[i] = Ag[i];
    }

    const int col0 = blockIdx.x*256 + wave*64 + cg*4;
    const float* bp7 = Bm + kblk*N + col0;
    float4 bA[4], bB[4];
    LOADB4(bA)                                   // in flight across the barrier wait

    __syncthreads();
    const float* ap7 = As + rg*8;

    float acc[32];
#pragma unroll
    for (int m = 0; m < 32; ++m) acc[m] = 0.f;

    float4 a0[2], a1[2];
    PREFA(a0, 0)

#pragma unroll 1
    for (int kk = 0; kk + 8 <= KB; kk += 8) {
        LOADB4(bB)
        PREFA(a1, kk+1) FMACK(a0, bA[0])
        PREFA(a0, kk+2) FMACK(a1, bA[1])
        PREFA(a1, kk+3) FMACK(a0, bA[2])
        PREFA(a0, kk+4) FMACK(a1, bA[3])
        if (kk + 8 < KB) { LOADB4(bA) }
        PREFA(a1, kk+5) FMACK(a0, bB[0])
        PREFA(a0, kk+6) FMACK(a1, bB[1])
        PREFA(a1, kk+7) FMACK(a0, bB[2])
        PREFA(a0, kk+8) FMACK(a1, bB[3])         // tail read hits the pad
    }

    // epilogue: direct partial store, 8 x float4 per thread. Each wave's 8
    // instrs fully cover its 8KB region -> L2 write-combines to full lines.
    float* p0 = P + (size_t)blockIdx.y*((size_t)N*32) + (size_t)col0*32 + rg*8;
#pragma unroll
    for (int c = 0; c < 4; ++c) {
        *(float4*)(p0 + c*32)     = make_float4(acc[c], acc[4+c], acc[8+c], acc[12+c]);
        *(float4*)(p0 + c*32 + 4) = make_float4(acc[16+c], acc[20+c], acc[24+c], acc[28+c]);
    }
}

// out[idx] = bias[idx>>5] + sum_y P[y][idx]
template<int Y>
__global__ void reduce_bias_k(const float* __restrict__ P, const float* __restrict__ bias,
                              float* __restrict__ out, int SZ) {
    int idx = blockIdx.x*256 + threadIdx.x;
    float s = bias[idx >> 5];
#pragma unroll 16
    for (int y = 0; y < Y; ++y) s += P[(size_t)y*SZ + idx];
    out[idx] = s;
}

// z and f=relu(z) in one pass (SZ=98304)
template<int Y>
__global__ void reduce_zf_k(const float* __restrict__ P, const float* __restrict__ bias,
                            float* __restrict__ zT, float* __restrict__ fT) {
    int idx = blockIdx.x*256 + threadIdx.x;
    float s = bias[idx >> 5];
#pragma unroll 16
    for (int y = 0; y < Y; ++y) s += P[(size_t)y*98304 + idx];
    zT[idx] = s;
    fT[idx] = fmaxf(s, 0.f);
}

// out = init + sum_y P
template<int Y>
__global__ void reduce_arr_k(const float* __restrict__ P, const float* __restrict__ init,
                             float* __restrict__ out, int SZ) {
    int idx = blockIdx.x*256 + threadIdx.x;
    float s = init[idx];
#pragma unroll 16
    for (int y = 0; y < Y; ++y) s += P[(size_t)y*SZ + idx];
    out[idx] = s;
}

// dfT = (z>0) ? (init + sum_y P) : 0     (SZ=98304)
template<int Y>
__global__ void reduce_mask_k(const float* __restrict__ P, const float* __restrict__ init,
                              const float* __restrict__ zT, float* __restrict__ dfT) {
    int idx = blockIdx.x*256 + threadIdx.x;
    float s = init[idx];
#pragma unroll 16
    for (int y = 0; y < Y; ++y) s += P[(size_t)y*98304 + idx];
    dfT[idx] = zT[idx] > 0.f ? s : 0.f;
}

// out[b,n] = base + init + sum_y P   (un-transpose on store)
template<int Y>
__global__ void reduce_out_k(const float* __restrict__ P, const float* __restrict__ init,
                             const float* __restrict__ baseT, float* __restrict__ out) {
    int idx = blockIdx.x*256 + threadIdx.x;   // 24576
    float s = init[idx] + baseT[idx];
#pragma unroll 16
    for (int y = 0; y < Y; ++y) s += P[(size_t)y*24576 + idx];
    int n = idx >> 5, b = idx & 31;
    out[b*768 + n] = s;
}

// MetaNet layer 1: v[b,j] = relu(mb1[j] + sum_i base[b,i]*mW1[i,j])
__global__ void metanet1_k(const float* __restrict__ baseT, const float* __restrict__ mW1,
                           const float* __restrict__ mb1, float* __restrict__ v) {
    int b  = blockIdx.x;
    int jg = blockIdx.y;
    int jj = threadIdx.x & 31;
    int ks = threadIdx.x >> 5;              // 0..7
    int j  = jg*32 + jj;
    const float* wp = mW1 + (size_t)(ks*96)*192 + j;   // coalesced 128B/segment
    const float* xp = baseT + (size_t)(ks*96)*32 + b;  // same-addr broadcast
    float s = 0.f;
#pragma unroll 8
    for (int i = 0; i < 96; ++i) s += xp[i*32] * wp[i*192];
    __shared__ float red[256];
    red[threadIdx.x] = s;
    __syncthreads();
    if (threadIdx.x < 32) {
        float t = mb1[j];
#pragma unroll
        for (int k = 0; k < 8; ++k) t += red[k*32 + threadIdx.x];
        v[b*192 + jg*32 + threadIdx.x] = fmaxf(t, 0.f);
    }
}

// MetaNet layer 2: coefs[b,o] = mb2[o] + sum_i v[b,i]*mW2[i,o]
__global__ void metanet2_k(const float* __restrict__ v, const float* __restrict__ mW2,
                           const float* __restrict__ mb2, float* __restrict__ coefs) {
    int b  = blockIdx.x;
    int o  = threadIdx.x & 63;
    int ks = threadIdx.x >> 6;              // 0..3
    float s = 0.f;
    if (o < 48) {
        const float* vp = v + b*192 + ks*48;
        const float* wp = mW2 + (size_t)(ks*48)*48 + o;
#pragma unroll 8
        for (int i = 0; i < 48; ++i) s += vp[i] * wp[i*48];
    }
    __shared__ float red[256];
    red[threadIdx.x] = s;
    __syncthreads();
    if (threadIdx.x < 48) {
        float t = mb2[threadIdx.x];
#pragma unroll
        for (int k = 0; k < 4; ++k) t += red[k*64 + threadIdx.x];
        coefs[b*48 + threadIdx.x] = t;
    }
}

// G0T/G1T/G2T (coef-scaled A operands) + delta-bias accumulator inits.
__global__ void build_all_k(const float* __restrict__ coefs, const float* __restrict__ xbarT,
                            const float* __restrict__ f0T, const float* __restrict__ fT,
                            const float* __restrict__ dbp, const float* __restrict__ db1,
                            const float* __restrict__ db2,
                            float* __restrict__ G0T, float* __restrict__ G1T,
                            float* __restrict__ G2T, float* __restrict__ df0b,
                            float* __restrict__ dzb, float* __restrict__ doutb) {
    int idx = blockIdx.x*256 + threadIdx.x;   // 1327104 total
    int b = idx & 31;
    int r = idx >> 5;
    if (r < 6144) {
        int t = r / 768, i = r % 768;
        G0T[idx] = coefs[b*48 + t*6 + 0] * xbarT[(size_t)i*32 + b];
    } else if (r < 12288) {
        int rr = r - 6144;
        int t = rr / 768, i = rr % 768;
        G1T[(size_t)rr*32 + b] = coefs[b*48 + t*6 + 2] * f0T[(size_t)i*32 + b];
    } else if (r < 36864) {
        int rr = r - 12288;
        int t = rr / 3072, i = rr % 3072;
        G2T[(size_t)rr*32 + b] = coefs[b*48 + t*6 + 4] * fT[(size_t)i*32 + b];
    } else if (r < 37632) {
        int n = r - 36864;
        float s = 0.f;
#pragma unroll
        for (int t = 0; t < 8; ++t) s += coefs[b*48 + t*6 + 1] * dbp[t*768 + n];
        df0b[(size_t)n*32 + b] = s;
    } else if (r < 40704) {
        int n = r - 37632;
        float s = 0.f;
#pragma unroll
        for (int t = 0; t < 8; ++t) s += coefs[b*48 + t*6 + 3] * db1[t*3072 + n];
        dzb[(size_t)n*32 + b] = s;
    } else if (r < 41472) {
        int n = r - 40704;
        float s = 0.f;
#pragma unroll
        for (int t = 0; t < 8; ++t) s += coefs[b*48 + t*6 + 5] * db2[t*768 + n];
        doutb[(size_t)n*32 + b] = s;
    }
}

extern "C" void kernel_launch(void* const* d_in, const int* in_sizes, int n_in,
                              void* d_out, int out_size, void* d_ws, size_t ws_size,
                              hipStream_t stream) {
    const float* x   = (const float*)d_in[0];
    const float* Wp  = (const float*)d_in[1];
    const float* bp  = (const float*)d_in[2];
    const float* W1  = (const float*)d_in[3];
    const float* b1  = (const float*)d_in[4];
    const float* W2  = (const float*)d_in[5];
    const float* b2  = (const float*)d_in[6];
    const float* dWp = (const float*)d_in[7];
    const float* dbp = (const float*)d_in[8];
    const float* dW1 = (const float*)d_in[9];
    const float* db1 = (const float*)d_in[10];
    const float* dW2 = (const float*)d_in[11];
    const float* db2 = (const float*)d_in[12];
    const float* mW1 = (const float*)d_in[13];
    const float* mb1 = (const float*)d_in[14];
    const float* mW2 = (const float*)d_in[15];
    const float* mb2 = (const float*)d_in[16];
    float* out = (float*)d_out;

    float* ws    = (float*)d_ws;
    float* part  = ws;                 // 344064
    float* xbarT = part  + 344064;     // 24576   [768,32]
    float* f0T   = xbarT + 24576;      // 24576
    float* zT    = f0T   + 24576;      // 98304
    float* fT    = zT    + 98304;      // 98304
    float* baseT = fT    + 98304;      // 24576
    float* coefs = baseT + 24576;      // 1536
    float* G0T   = coefs + 1536;       // 196608  [6144,32]
    float* G1T   = G0T   + 196608;     // 196608  [6144,32]
    float* G2T   = G1T   + 196608;     // 786432  [24576,32]
    float* df0b  = G2T   + 786432;     // 24576
    float* dzb   = df0b  + 24576;      // 98304
    float* doutb = dzb   + 98304;      // 24576
    float* dfT   = doutb + 24576;      // 98304
    float* df0T  = dfT   + 98304;      // 24576
    float* mv    = df0T  + 24576;      // 6144    : MetaNet hidden v[32,192]
    // partial arenas (reused across phases; no lifetime overlap)
    float* A1 = mv + 6144;                    // 80 slices of 98304 : Pz(16), then Pdz(16+64)
    float* A2 = A1 + (size_t)80*98304;        // 320 slices of 24576: Pbase(64), then Pdout(64+256)
    float* A3 = A2 + (size_t)320*24576;       // 128 slices of 24576: Pf0(16), then Pdf0(128)
    // total ~21M floats = ~84 MB (ws ~302 MB per fill counter)

    // 1) per-sample patch mean
    patch_partial_k<<<1344, 256, 0, stream>>>(x, part);
    patch_reduce_k<<<96, 256, 0, stream>>>(part, xbarT);

    // 2) base path
    gemm7_k<768, 48><<<dim3(3, 16), 256, 0, stream>>>(xbarT, Wp, A3);    // K=768, 16 slices
    reduce_bias_k<16><<<96, 256, 0, stream>>>(A3, bp, f0T, 24576);
    gemm7_k<3072, 48><<<dim3(12, 16), 256, 0, stream>>>(f0T, W1, A1);    // K=768, 16 slices
    reduce_zf_k<16><<<384, 256, 0, stream>>>(A1, b1, zT, fT);
    gemm7_k<768, 48><<<dim3(3, 64), 256, 0, stream>>>(fT, W2, A2);       // K=3072, 64 slices
    reduce_bias_k<64><<<96, 256, 0, stream>>>(A2, b2, baseT, 24576);

    // 3) MetaNet coefficients
    metanet1_k<<<dim3(32, 6), 256, 0, stream>>>(baseT, mW1, mb1, mv);
    metanet2_k<<<32, 256, 0, stream>>>(mv, mW2, mb2, coefs);

    // 4) scaled A-operands + delta-bias inits
    build_all_k<<<5184, 256, 0, stream>>>(coefs, xbarT, f0T, fT, dbp, db1, db2,
                                          G0T, G1T, G2T, df0b, dzb, doutb);

    // 5) JVP chain
    gemm7_k<768, 48><<<dim3(3, 128), 256, 0, stream>>>(G0T, dWp, A3);    // K=6144, 128 slices
    reduce_arr_k<128><<<96, 256, 0, stream>>>(A3, df0b, df0T, 24576);
    gemm7_k<3072, 48><<<dim3(12, 16), 256, 0, stream>>>(df0T, W1, A1);   // K=768, slices 0..16
    gemm7_k<3072, 96><<<dim3(12, 64), 256, 0, stream>>>(G1T, dW1, A1 + (size_t)16*98304); // K=6144, 16..80
    reduce_mask_k<80><<<384, 256, 0, stream>>>(A1, dzb, zT, dfT);
    gemm7_k<768, 48><<<dim3(3, 64), 256, 0, stream>>>(dfT, W2, A2);      // K=3072, slices 0..64
    gemm7_k<768, 96><<<dim3(3, 256), 256, 0, stream>>>(G2T, dW2, A2 + (size_t)64*24576); // K=24576, 64..320
    reduce_out_k<320><<<96, 256, 0, stream>>>(A2, doutb, baseT, out);
}